// Round 6
// baseline (380.656 us; speedup 1.0000x reference)
//
#include <hip/hip_runtime.h>

#define N_VEC 131072   // B*H*W
#define DIM   64
#define KCODE 1024
#define HW    4096
#define DHW   262144
#define EPS   0.125f   // near-tie margin (~6x worst-case packing+bf16x3 error)
#define WLCAP 32768
#define BLK_ROWS 128   // rows per block; 2 waves x 64 rows
#define PITCH 72       // shorts per LDS row (144 B = 9*16B: aligned, 2-way-max frag reads)
#define RV 16          // vectors per rescue chunk

typedef short short8 __attribute__((ext_vector_type(8)));
typedef float f32x4  __attribute__((ext_vector_type(4)));

// ws layout (bytes):
//   0      : double loss accumulator
//   8      : int flagged counter
//   12     : int done-ticket counter
//   64     : norms f32[1024]
//   8192   : eh  bf16-bits short[65536]
//   139264 : el  bf16-bits short[65536]
//   270336 : worklist int[WLCAP]

__device__ __forceinline__ unsigned short f32_to_bf16_rne(float x) {
    unsigned u = __float_as_uint(x);
    u += 0x7FFFu + ((u >> 16) & 1u);
    return (unsigned short)(u >> 16);
}
__device__ __forceinline__ float bf16_to_f32(unsigned short h) {
    return __uint_as_float((unsigned)h << 16);
}

// 64 blocks x 256 threads: code k = blk*16 + t>>4, part = t&15 -> 4 d's.
// Block 0 also zeroes the accumulators (replaces hipMemsetAsync node).
__global__ __launch_bounds__(256) void vq_prep(
    const float* __restrict__ cb, float* __restrict__ norms,
    short* __restrict__ ehg, short* __restrict__ elg,
    double* __restrict__ loss_acc, int* __restrict__ counter,
    int* __restrict__ done)
{
    const int t = threadIdx.x;
    if (blockIdx.x == 0 && t == 0) { *loss_acc = 0.0; *counter = 0; *done = 0; }

    const int k    = blockIdx.x * 16 + (t >> 4);
    const int part = t & 15;
    const float4 v = *(const float4*)(cb + k * DIM + part * 4);

    float s = 0.f;
    s = fmaf(v.x, v.x, s); s = fmaf(v.y, v.y, s);
    s = fmaf(v.z, v.z, s); s = fmaf(v.w, v.w, s);
    #pragma unroll
    for (int m = 1; m <= 8; m <<= 1) s += __shfl_xor(s, m, 64);
    if (part == 0) norms[k] = s;

    short h[4], l[4];
    const float vv[4] = { v.x, v.y, v.z, v.w };
    #pragma unroll
    for (int j = 0; j < 4; ++j) {
        unsigned short hh = f32_to_bf16_rne(vv[j]);
        unsigned short ll = f32_to_bf16_rne(vv[j] - bf16_to_f32(hh));
        h[j] = (short)hh; l[j] = (short)ll;
    }
    *(short4*)(ehg + k * DIM + part * 4) = make_short4(h[0], h[1], h[2], h[3]);
    *(short4*)(elg + k * DIM + part * 4) = make_short4(l[0], l[1], l[2], l[3]);
}

__global__ __launch_bounds__(128, 2) void vq_main(
    const float* __restrict__ z, const float* __restrict__ cb,
    const float* __restrict__ norms, const short* __restrict__ ehg,
    const short* __restrict__ elg, float* __restrict__ out,
    double* __restrict__ loss_acc, int* __restrict__ counter,
    int* __restrict__ worklist, int cap)
{
    __shared__ short zh[BLK_ROWS * PITCH];   // bf16 bits of hi(-2z), [row=hw][d]
    __shared__ short zl[BLK_ROWS * PITCH];
    __shared__ int   kidx[BLK_ROWS];
    __shared__ float wsum[2];

    const int t   = threadIdx.x;          // 0..127
    const int n0  = blockIdx.x * BLK_ROWS;
    const int b   = n0 >> 12;
    const int hw0 = n0 & 4095;

    // ---- stage: 16 independent float4 loads, register transpose, b128 writes ----
    {
        const int hwl   = (t & 31) * 4;      // 4 consecutive rows
        const int dbase = (t >> 5) * 16;     // 16 consecutive d
        float4 v[16];
        #pragma unroll
        for (int p = 0; p < 16; ++p)
            v[p] = *(const float4*)(z + (size_t)b * DHW + (size_t)(dbase + p) * HW + hw0 + hwl);
        #pragma unroll
        for (int c = 0; c < 4; ++c) {
            short8 hi[2], lo[2];
            #pragma unroll
            for (int p = 0; p < 16; ++p) {
                const float* vp = (const float*)&v[p];
                float f = -2.0f * vp[c];
                unsigned short hh = f32_to_bf16_rne(f);
                unsigned short ll = f32_to_bf16_rne(f - bf16_to_f32(hh));
                hi[p >> 3][p & 7] = (short)hh;
                lo[p >> 3][p & 7] = (short)ll;
            }
            const int base = (hwl + c) * PITCH + dbase;
            *(short8*)&zh[base]     = hi[0];
            *(short8*)&zh[base + 8] = hi[1];
            *(short8*)&zl[base]     = lo[0];
            *(short8*)&zl[base + 8] = lo[1];
        }
    }
    __syncthreads();

    const int lane = t & 63;
    const int wave = t >> 6;              // 0..1
    const int l15  = lane & 15;
    const int quad = lane >> 4;
    const int rowbase = wave * 64;        // each wave owns 64 rows (4 row-tiles)

    // ---- A-fragments (registers for whole scan): 4 rt x 2 kt x {hi,lo} ----
    short8 a_h[4][2], a_l[4][2];
    #pragma unroll
    for (int rt = 0; rt < 4; ++rt)
        #pragma unroll
        for (int kt = 0; kt < 2; ++kt) {
            int idx = (rowbase + rt * 16 + l15) * PITCH + kt * 32 + quad * 8;
            a_h[rt][kt] = *(const short8*)&zh[idx];
            a_l[rt][kt] = *(const short8*)&zl[idx];
        }

    float best[4][4], best2[4][4];
    #pragma unroll
    for (int rt = 0; rt < 4; ++rt)
        #pragma unroll
        for (int r = 0; r < 4; ++r) { best[rt][r] = 3.0e38f; best2[rt][r] = 3.0e38f; }

    // ---- scan: 64 code-tiles, double-buffered B prefetch ----
    const short* bhbase = ehg + l15 * DIM + quad * 8;
    const short* blbase = elg + l15 * DIM + quad * 8;
    const float* nrmp   = norms + l15;

    short8 B[2][4];
    float  NR[2];
    B[0][0] = *(const short8*)(bhbase);
    B[0][1] = *(const short8*)(bhbase + 32);
    B[0][2] = *(const short8*)(blbase);
    B[0][3] = *(const short8*)(blbase + 32);
    NR[0]   = nrmp[0];

#define VQ_COMPUTE(BUF, TILE)                                                        \
    {                                                                                \
        const unsigned colbits = (unsigned)((TILE) * 16 + l15);                      \
        _Pragma("unroll")                                                            \
        for (int rt = 0; rt < 4; ++rt) {                                             \
            f32x4 acc = { NR[BUF], NR[BUF], NR[BUF], NR[BUF] };                      \
            acc = __builtin_amdgcn_mfma_f32_16x16x32_bf16(a_h[rt][0], B[BUF][0], acc, 0, 0, 0); \
            acc = __builtin_amdgcn_mfma_f32_16x16x32_bf16(a_h[rt][1], B[BUF][1], acc, 0, 0, 0); \
            acc = __builtin_amdgcn_mfma_f32_16x16x32_bf16(a_h[rt][0], B[BUF][2], acc, 0, 0, 0); \
            acc = __builtin_amdgcn_mfma_f32_16x16x32_bf16(a_h[rt][1], B[BUF][3], acc, 0, 0, 0); \
            acc = __builtin_amdgcn_mfma_f32_16x16x32_bf16(a_l[rt][0], B[BUF][0], acc, 0, 0, 0); \
            acc = __builtin_amdgcn_mfma_f32_16x16x32_bf16(a_l[rt][1], B[BUF][1], acc, 0, 0, 0); \
            _Pragma("unroll")                                                        \
            for (int r = 0; r < 4; ++r) {                                            \
                float p = __uint_as_float((__float_as_uint(acc[r]) & 0xFFFFFC00u) | colbits); \
                best2[rt][r] = fminf(best2[rt][r], fmaxf(best[rt][r], p));           \
                best[rt][r]  = fminf(best[rt][r], p);                                \
            }                                                                        \
        }                                                                            \
    }

    for (int tile = 0; tile < 64; tile += 2) {
        {
            const short* p = bhbase + (tile + 1) * 1024;
            const short* q = blbase + (tile + 1) * 1024;
            B[1][0] = *(const short8*)(p);
            B[1][1] = *(const short8*)(p + 32);
            B[1][2] = *(const short8*)(q);
            B[1][3] = *(const short8*)(q + 32);
            NR[1]   = nrmp[(tile + 1) * 16];
        }
        VQ_COMPUTE(0, tile)
        if (tile + 2 < 64) {
            const short* p = bhbase + (tile + 2) * 1024;
            const short* q = blbase + (tile + 2) * 1024;
            B[0][0] = *(const short8*)(p);
            B[0][1] = *(const short8*)(p + 32);
            B[0][2] = *(const short8*)(q);
            B[0][3] = *(const short8*)(q + 32);
            NR[0]   = nrmp[(tile + 2) * 16];
        }
        VQ_COMPUTE(1, tile + 1)
    }
#undef VQ_COMPUTE

    // ---- cross-lane top-2 merge (cols live in 16-lane groups) ----
    #pragma unroll
    for (int rt = 0; rt < 4; ++rt)
        #pragma unroll
        for (int r = 0; r < 4; ++r) {
            float bb = best[rt][r], b2 = best2[rt][r];
            #pragma unroll
            for (int m = 1; m <= 8; m <<= 1) {
                float ob  = __shfl_xor(bb, m, 64);
                float ob2 = __shfl_xor(b2, m, 64);
                b2 = fminf(fminf(b2, ob2), fmaxf(bb, ob));
                bb = fminf(bb, ob);
            }
            best[rt][r] = bb; best2[rt][r] = b2;
        }

    // ---- per-row result: index, flag, worklist ----
    if (l15 == 0) {
        #pragma unroll
        for (int rt = 0; rt < 4; ++rt)
            #pragma unroll
            for (int r = 0; r < 4; ++r) {
                unsigned ub = __float_as_uint(best[rt][r]);
                int k = (int)(ub & 1023u);
                float sb  = __uint_as_float(ub & 0xFFFFFC00u);
                float sb2 = __uint_as_float(__float_as_uint(best2[rt][r]) & 0xFFFFFC00u);
                int rowl = rt * 16 + quad * 4 + r;
                int flag = 0;
                if (sb2 - sb < EPS) {
                    int slot = atomicAdd(counter, 1);
                    if (slot < cap) { worklist[slot] = n0 + rowbase + rowl; flag = 1; }
                }
                kidx[rowbase + rowl] = k | (flag << 15);
            }
    }
    __syncthreads();

    // ---- epilogue: 1 lane = 1 row; b128 z-row reads, float4 cb-row reads ----
    float lsum = 0.f;
    {
        const int rowl = rowbase + lane;
        const int ki   = kidx[rowl];
        const int k    = ki & 1023;
        const int flag = (ki >> 15) & 1;
        if (!flag) {
            const float4*  cbr = (const float4*)(cb + k * DIM);
            const short8*  zhr = (const short8*)&zh[rowl * PITCH];
            const short8*  zlr = (const short8*)&zl[rowl * PITCH];
            float* op = out + (size_t)b * DHW + hw0 + rowl;
            #pragma unroll
            for (int g = 0; g < 8; ++g) {
                short8 hh = zhr[g];
                short8 ll = zlr[g];
                float4 e0 = cbr[2 * g];
                float4 e1 = cbr[2 * g + 1];
                const float ev[8] = { e0.x, e0.y, e0.z, e0.w, e1.x, e1.y, e1.z, e1.w };
                #pragma unroll
                for (int j = 0; j < 8; ++j) {
                    float zv = -0.5f * (bf16_to_f32((unsigned short)hh[j]) +
                                        bf16_to_f32((unsigned short)ll[j]));
                    op[(size_t)(g * 8 + j) * HW] = ev[j];
                    float df = ev[j] - zv;
                    lsum = fmaf(df, df, lsum);
                }
            }
        }
    }
    #pragma unroll
    for (int off = 32; off > 0; off >>= 1) lsum += __shfl_down(lsum, off, 64);
    if (lane == 0) wsum[wave] = lsum;
    __syncthreads();
    if (t == 0) atomicAdd(loss_acc, (double)(wsum[0] + wsum[1]));
}

// Exact f64 rescan for flagged vectors; grid-stride over RV-chunks;
// last-finished block finalizes the loss (replaces vq_finalize node).
__global__ __launch_bounds__(256) void vq_rescue(
    const float* __restrict__ z, const float* __restrict__ cb,
    float* __restrict__ out, double* __restrict__ loss_acc,
    const int* __restrict__ counter, const int* __restrict__ worklist, int cap,
    int* __restrict__ done, float* __restrict__ loss_out)
{
    __shared__ float  cbs[128 * DIM];
    __shared__ float  zsv[RV * DIM];
    __shared__ double rvals[256];
    __shared__ int    ridx[256];
    __shared__ int    rn[RV];
    __shared__ int    ticket_s;

    int count = *counter; if (count > cap) count = cap;

    const int t   = threadIdx.x;
    const int v   = t & 15;
    const int sub = t >> 4;

    for (int base = blockIdx.x * RV; base < count; base += gridDim.x * RV) {
        int nv = count - base; if (nv > RV) nv = RV;

        if (t < nv) rn[t] = worklist[base + t];
        __syncthreads();
        if (v < nv) {
            const int n = rn[v];
            const int bb = n >> 12, hw = n & 4095;
            #pragma unroll
            for (int j = 0; j < 4; ++j) {
                int d = sub * 4 + j;
                zsv[v * DIM + d] = z[(size_t)bb * DHW + (size_t)d * HW + hw];
            }
        }
        __syncthreads();

        double bestd = 1e300; int bestk = 0;
        for (int chunk = 0; chunk < 8; ++chunk) {
            const float4* src = (const float4*)(cb + chunk * 128 * DIM);
            float4* dst = (float4*)cbs;
            for (int i = t; i < 128 * DIM / 4; i += 256) dst[i] = src[i];
            __syncthreads();
            if (v < nv) {
                for (int j = 0; j < 8; ++j) {
                    const int c = sub * 8 + j;
                    const float* cr = cbs + c * DIM;
                    const float* zr = zsv + v * DIM;
                    double s = 0.0;
                    for (int d = 0; d < DIM; ++d) {
                        double diff = (double)zr[d] - (double)cr[d];
                        s = fma(diff, diff, s);
                    }
                    const int gk = chunk * 128 + c;
                    if (s < bestd) { bestd = s; bestk = gk; }
                }
            }
            __syncthreads();
        }
        rvals[t] = bestd; ridx[t] = bestk;
        __syncthreads();
        for (int s = 8; s > 0; s >>= 1) {
            if (sub < s) {
                double ov = rvals[t + 16 * s]; int oi = ridx[t + 16 * s];
                if (ov < rvals[t] || (ov == rvals[t] && oi < ridx[t])) {
                    rvals[t] = ov; ridx[t] = oi;
                }
            }
            __syncthreads();
        }
        if (v < nv) {
            const int n = rn[v];
            const int bb = n >> 12, hw = n & 4095;
            const int kb = ridx[v];
            #pragma unroll
            for (int j = 0; j < 4; ++j) {
                int d = sub * 4 + j;
                out[(size_t)bb * DHW + (size_t)d * HW + hw] = cb[kb * DIM + d];
            }
            if (sub == 0) atomicAdd(loss_acc, rvals[v]);
        }
        __syncthreads();
    }

    // ---- last-block ticket -> finalize loss ----
    __threadfence();
    if (t == 0) ticket_s = atomicAdd(done, 1);
    __syncthreads();
    if (t == 0 && ticket_s == (int)gridDim.x - 1) {
        double total = atomicAdd(loss_acc, 0.0);   // device-coherent read
        *loss_out = (float)(1.25 * total * (1.0 / (double)((long)N_VEC * DIM)));
    }
}

extern "C" void kernel_launch(void* const* d_in, const int* in_sizes, int n_in,
                              void* d_out, int out_size, void* d_ws, size_t ws_size,
                              hipStream_t stream) {
    const float* z  = (const float*)d_in[0];
    const float* cb = (const float*)d_in[1];
    float* out      = (float*)d_out;
    char*  ws       = (char*)d_ws;

    double* loss_acc = (double*)ws;
    int*    counter  = (int*)(ws + 8);
    int*    done     = (int*)(ws + 12);
    float*  norms    = (float*)(ws + 64);
    short*  ehg      = (short*)(ws + 8192);
    short*  elg      = (short*)(ws + 139264);
    int*    worklist = (int*)(ws + 270336);

    int cap = WLCAP;
    long avail = ((long)ws_size - 270336) / 4;
    if (avail < cap) cap = (avail > 0) ? (int)avail : 0;

    vq_prep<<<dim3(KCODE / 16), dim3(256), 0, stream>>>(
        cb, norms, ehg, elg, loss_acc, counter, done);
    vq_main<<<dim3(N_VEC / BLK_ROWS), dim3(128), 0, stream>>>(
        z, cb, norms, ehg, elg, out, loss_acc, counter, worklist, cap);
    vq_rescue<<<dim3(512), dim3(256), 0, stream>>>(
        z, cb, out, loss_acc, counter, worklist, cap, done, out + (out_size - 1));
}

// Round 7
// 298.652 us; speedup vs baseline: 1.2746x; 1.2746x over previous
//
#include <hip/hip_runtime.h>

#define N_VEC 131072   // B*H*W
#define DIM   64
#define KCODE 1024
#define HW    4096
#define DHW   262144
#define EPS   0.125f   // near-tie margin (validated r4/r6)
#define WLCAP 32768
#define BLK_ROWS 128   // rows per block; 2 waves x 64 rows
#define PITCH 72       // shorts per LDS row (144 B = 9*16B)
#define CPITCH 65      // floats per rescue-LDS codebook row (odd -> conflict-free)
#define CHUNK_ROWS 256

typedef short short8 __attribute__((ext_vector_type(8)));
typedef float f32x4  __attribute__((ext_vector_type(4)));

// ws layout (bytes):
//   0      : double loss accumulator
//   8      : int flagged counter
//   12     : int done-ticket counter
//   64     : norms f32[1024]
//   8192   : eh  bf16-bits short[65536]
//   139264 : el  bf16-bits short[65536]
//   270336 : worklist int[WLCAP]

__device__ __forceinline__ unsigned short f32_to_bf16_rne(float x) {
    unsigned u = __float_as_uint(x);
    u += 0x7FFFu + ((u >> 16) & 1u);
    return (unsigned short)(u >> 16);
}
__device__ __forceinline__ float bf16_to_f32(unsigned short h) {
    return __uint_as_float((unsigned)h << 16);
}

__global__ __launch_bounds__(256) void vq_prep(
    const float* __restrict__ cb, float* __restrict__ norms,
    short* __restrict__ ehg, short* __restrict__ elg,
    double* __restrict__ loss_acc, int* __restrict__ counter,
    int* __restrict__ done)
{
    const int t = threadIdx.x;
    if (blockIdx.x == 0 && t == 0) { *loss_acc = 0.0; *counter = 0; *done = 0; }

    const int k    = blockIdx.x * 16 + (t >> 4);
    const int part = t & 15;
    const float4 v = *(const float4*)(cb + k * DIM + part * 4);

    float s = 0.f;
    s = fmaf(v.x, v.x, s); s = fmaf(v.y, v.y, s);
    s = fmaf(v.z, v.z, s); s = fmaf(v.w, v.w, s);
    #pragma unroll
    for (int m = 1; m <= 8; m <<= 1) s += __shfl_xor(s, m, 64);
    if (part == 0) norms[k] = s;

    short h[4], l[4];
    const float vv[4] = { v.x, v.y, v.z, v.w };
    #pragma unroll
    for (int j = 0; j < 4; ++j) {
        unsigned short hh = f32_to_bf16_rne(vv[j]);
        unsigned short ll = f32_to_bf16_rne(vv[j] - bf16_to_f32(hh));
        h[j] = (short)hh; l[j] = (short)ll;
    }
    *(short4*)(ehg + k * DIM + part * 4) = make_short4(h[0], h[1], h[2], h[3]);
    *(short4*)(elg + k * DIM + part * 4) = make_short4(l[0], l[1], l[2], l[3]);
}

__global__ __launch_bounds__(128, 2) void vq_main(
    const float* __restrict__ z, const float* __restrict__ cb,
    const float* __restrict__ norms, const short* __restrict__ ehg,
    const short* __restrict__ elg, float* __restrict__ out,
    double* __restrict__ loss_acc, int* __restrict__ counter,
    int* __restrict__ worklist, int cap)
{
    __shared__ short zh[BLK_ROWS * PITCH];
    __shared__ short zl[BLK_ROWS * PITCH];
    __shared__ int   kidx[BLK_ROWS];
    __shared__ float wsum[2];

    const int t   = threadIdx.x;
    const int n0  = blockIdx.x * BLK_ROWS;
    const int b   = n0 >> 12;
    const int hw0 = n0 & 4095;

    {
        const int hwl   = (t & 31) * 4;
        const int dbase = (t >> 5) * 16;
        float4 v[16];
        #pragma unroll
        for (int p = 0; p < 16; ++p)
            v[p] = *(const float4*)(z + (size_t)b * DHW + (size_t)(dbase + p) * HW + hw0 + hwl);
        #pragma unroll
        for (int c = 0; c < 4; ++c) {
            short8 hi[2], lo[2];
            #pragma unroll
            for (int p = 0; p < 16; ++p) {
                const float* vp = (const float*)&v[p];
                float f = -2.0f * vp[c];
                unsigned short hh = f32_to_bf16_rne(f);
                unsigned short ll = f32_to_bf16_rne(f - bf16_to_f32(hh));
                hi[p >> 3][p & 7] = (short)hh;
                lo[p >> 3][p & 7] = (short)ll;
            }
            const int base = (hwl + c) * PITCH + dbase;
            *(short8*)&zh[base]     = hi[0];
            *(short8*)&zh[base + 8] = hi[1];
            *(short8*)&zl[base]     = lo[0];
            *(short8*)&zl[base + 8] = lo[1];
        }
    }
    __syncthreads();

    const int lane = t & 63;
    const int wave = t >> 6;
    const int l15  = lane & 15;
    const int quad = lane >> 4;
    const int rowbase = wave * 64;

    short8 a_h[4][2], a_l[4][2];
    #pragma unroll
    for (int rt = 0; rt < 4; ++rt)
        #pragma unroll
        for (int kt = 0; kt < 2; ++kt) {
            int idx = (rowbase + rt * 16 + l15) * PITCH + kt * 32 + quad * 8;
            a_h[rt][kt] = *(const short8*)&zh[idx];
            a_l[rt][kt] = *(const short8*)&zl[idx];
        }

    float best[4][4], best2[4][4];
    #pragma unroll
    for (int rt = 0; rt < 4; ++rt)
        #pragma unroll
        for (int r = 0; r < 4; ++r) { best[rt][r] = 3.0e38f; best2[rt][r] = 3.0e38f; }

    const short* bhbase = ehg + l15 * DIM + quad * 8;
    const short* blbase = elg + l15 * DIM + quad * 8;
    const float* nrmp   = norms + l15;

    short8 B[2][4];
    float  NR[2];
    B[0][0] = *(const short8*)(bhbase);
    B[0][1] = *(const short8*)(bhbase + 32);
    B[0][2] = *(const short8*)(blbase);
    B[0][3] = *(const short8*)(blbase + 32);
    NR[0]   = nrmp[0];

#define VQ_COMPUTE(BUF, TILE)                                                        \
    {                                                                                \
        const unsigned colbits = (unsigned)((TILE) * 16 + l15);                      \
        _Pragma("unroll")                                                            \
        for (int rt = 0; rt < 4; ++rt) {                                             \
            f32x4 acc = { NR[BUF], NR[BUF], NR[BUF], NR[BUF] };                      \
            acc = __builtin_amdgcn_mfma_f32_16x16x32_bf16(a_h[rt][0], B[BUF][0], acc, 0, 0, 0); \
            acc = __builtin_amdgcn_mfma_f32_16x16x32_bf16(a_h[rt][1], B[BUF][1], acc, 0, 0, 0); \
            acc = __builtin_amdgcn_mfma_f32_16x16x32_bf16(a_h[rt][0], B[BUF][2], acc, 0, 0, 0); \
            acc = __builtin_amdgcn_mfma_f32_16x16x32_bf16(a_h[rt][1], B[BUF][3], acc, 0, 0, 0); \
            acc = __builtin_amdgcn_mfma_f32_16x16x32_bf16(a_l[rt][0], B[BUF][0], acc, 0, 0, 0); \
            acc = __builtin_amdgcn_mfma_f32_16x16x32_bf16(a_l[rt][1], B[BUF][1], acc, 0, 0, 0); \
            _Pragma("unroll")                                                        \
            for (int r = 0; r < 4; ++r) {                                            \
                float p = __uint_as_float((__float_as_uint(acc[r]) & 0xFFFFFC00u) | colbits); \
                best2[rt][r] = fminf(best2[rt][r], fmaxf(best[rt][r], p));           \
                best[rt][r]  = fminf(best[rt][r], p);                                \
            }                                                                        \
        }                                                                            \
    }

    for (int tile = 0; tile < 64; tile += 2) {
        {
            const short* p = bhbase + (tile + 1) * 1024;
            const short* q = blbase + (tile + 1) * 1024;
            B[1][0] = *(const short8*)(p);
            B[1][1] = *(const short8*)(p + 32);
            B[1][2] = *(const short8*)(q);
            B[1][3] = *(const short8*)(q + 32);
            NR[1]   = nrmp[(tile + 1) * 16];
        }
        VQ_COMPUTE(0, tile)
        if (tile + 2 < 64) {
            const short* p = bhbase + (tile + 2) * 1024;
            const short* q = blbase + (tile + 2) * 1024;
            B[0][0] = *(const short8*)(p);
            B[0][1] = *(const short8*)(p + 32);
            B[0][2] = *(const short8*)(q);
            B[0][3] = *(const short8*)(q + 32);
            NR[0]   = nrmp[(tile + 2) * 16];
        }
        VQ_COMPUTE(1, tile + 1)
    }
#undef VQ_COMPUTE

    #pragma unroll
    for (int rt = 0; rt < 4; ++rt)
        #pragma unroll
        for (int r = 0; r < 4; ++r) {
            float bb = best[rt][r], b2 = best2[rt][r];
            #pragma unroll
            for (int m = 1; m <= 8; m <<= 1) {
                float ob  = __shfl_xor(bb, m, 64);
                float ob2 = __shfl_xor(b2, m, 64);
                b2 = fminf(fminf(b2, ob2), fmaxf(bb, ob));
                bb = fminf(bb, ob);
            }
            best[rt][r] = bb; best2[rt][r] = b2;
        }

    if (l15 == 0) {
        #pragma unroll
        for (int rt = 0; rt < 4; ++rt)
            #pragma unroll
            for (int r = 0; r < 4; ++r) {
                unsigned ub = __float_as_uint(best[rt][r]);
                int k = (int)(ub & 1023u);
                float sb  = __uint_as_float(ub & 0xFFFFFC00u);
                float sb2 = __uint_as_float(__float_as_uint(best2[rt][r]) & 0xFFFFFC00u);
                int rowl = rt * 16 + quad * 4 + r;
                int flag = 0;
                if (sb2 - sb < EPS) {
                    int slot = atomicAdd(counter, 1);
                    if (slot < cap) { worklist[slot] = n0 + rowbase + rowl; flag = 1; }
                }
                kidx[rowbase + rowl] = k | (flag << 15);
            }
    }
    __syncthreads();

    float lsum = 0.f;
    {
        const int rowl = rowbase + lane;
        const int ki   = kidx[rowl];
        const int k    = ki & 1023;
        const int flag = (ki >> 15) & 1;
        if (!flag) {
            const float4*  cbr = (const float4*)(cb + k * DIM);
            const short8*  zhr = (const short8*)&zh[rowl * PITCH];
            const short8*  zlr = (const short8*)&zl[rowl * PITCH];
            float* op = out + (size_t)b * DHW + hw0 + rowl;
            #pragma unroll
            for (int g = 0; g < 8; ++g) {
                short8 hh = zhr[g];
                short8 ll = zlr[g];
                float4 e0 = cbr[2 * g];
                float4 e1 = cbr[2 * g + 1];
                const float ev[8] = { e0.x, e0.y, e0.z, e0.w, e1.x, e1.y, e1.z, e1.w };
                #pragma unroll
                for (int j = 0; j < 8; ++j) {
                    float zv = -0.5f * (bf16_to_f32((unsigned short)hh[j]) +
                                        bf16_to_f32((unsigned short)ll[j]));
                    op[(size_t)(g * 8 + j) * HW] = ev[j];
                    float df = ev[j] - zv;
                    lsum = fmaf(df, df, lsum);
                }
            }
        }
    }
    #pragma unroll
    for (int off = 32; off > 0; off >>= 1) lsum += __shfl_down(lsum, off, 64);
    if (lane == 0) wsum[wave] = lsum;
    __syncthreads();
    if (t == 0) atomicAdd(loss_acc, (double)(wsum[0] + wsum[1]));
}

// One wave per flagged vector (4/block); codebook LDS-staged with odd pitch
// (conflict-free); exact f64 distances; last block finalizes the loss.
__global__ __launch_bounds__(256, 2) void vq_rescue(
    const float* __restrict__ z, const float* __restrict__ cb,
    float* __restrict__ out, double* __restrict__ loss_acc,
    const int* __restrict__ counter, const int* __restrict__ worklist, int cap,
    int* __restrict__ done, float* __restrict__ loss_out)
{
    __shared__ float cbs[CHUNK_ROWS * CPITCH];   // 65 KiB
    __shared__ float zsh[4][DIM];

    int count = *counter; if (count > cap) count = cap;
    const int t    = threadIdx.x;
    const int wave = t >> 6;
    const int lane = t & 63;

    for (int base = blockIdx.x * 4; base < count; base += gridDim.x * 4) {
        const int  i      = base + wave;
        const bool active = (i < count);          // wave-uniform
        int n = 0;
        if (active) {
            n = worklist[i];
            const int bb = n >> 12, hw = n & 4095;
            zsh[wave][lane] = z[(size_t)bb * DHW + (size_t)lane * HW + hw];
        }

        double bestd = 1e300; int bestk = 0;
        for (int chunk = 0; chunk < 4; ++chunk) {
            __syncthreads();   // cbs reusable + zsh visible (uniform trip counts)
            const float4* src = (const float4*)(cb + (size_t)chunk * CHUNK_ROWS * DIM);
            #pragma unroll
            for (int ii = 0; ii < 16; ++ii) {
                const int f   = t + ii * 256;     // float4 index in chunk
                float4 v = src[f];
                float* dst = &cbs[(f >> 4) * CPITCH + (f & 15) * 4];
                dst[0] = v.x; dst[1] = v.y; dst[2] = v.z; dst[3] = v.w;
            }
            __syncthreads();
            if (active) {
                const float* zr = zsh[wave];      // broadcast reads (free)
                #pragma unroll
                for (int j = 0; j < 4; ++j) {
                    const int row = j * 64 + lane;
                    const float* cr = &cbs[row * CPITCH];
                    double s0 = 0, s1 = 0, s2 = 0, s3 = 0;
                    #pragma unroll
                    for (int d = 0; d < DIM; d += 4) {
                        double d0 = (double)zr[d + 0] - (double)cr[d + 0];
                        double d1 = (double)zr[d + 1] - (double)cr[d + 1];
                        double d2 = (double)zr[d + 2] - (double)cr[d + 2];
                        double d3 = (double)zr[d + 3] - (double)cr[d + 3];
                        s0 = fma(d0, d0, s0); s1 = fma(d1, d1, s1);
                        s2 = fma(d2, d2, s2); s3 = fma(d3, d3, s3);
                    }
                    double s = (s0 + s1) + (s2 + s3);
                    const int gk = chunk * CHUNK_ROWS + row;
                    if (s < bestd) { bestd = s; bestk = gk; }
                }
            }
        }

        // wave-level (val, idx) min with first-occurrence tiebreak
        #pragma unroll
        for (int m = 1; m <= 32; m <<= 1) {
            double ov = __shfl_xor(bestd, m, 64);
            int    oi = __shfl_xor(bestk, m, 64);
            if (ov < bestd || (ov == bestd && oi < bestk)) { bestd = ov; bestk = oi; }
        }
        if (active) {
            const int bb = n >> 12, hw = n & 4095;
            out[(size_t)bb * DHW + (size_t)lane * HW + hw] = cb[bestk * DIM + lane];
            if (lane == 0) atomicAdd(loss_acc, bestd);
        }
    }

    __threadfence();
    __shared__ int ticket_s;
    if (t == 0) ticket_s = atomicAdd(done, 1);
    __syncthreads();
    if (t == 0 && ticket_s == (int)gridDim.x - 1) {
        double total = atomicAdd(loss_acc, 0.0);   // device-coherent read
        *loss_out = (float)(1.25 * total * (1.0 / (double)((long)N_VEC * DIM)));
    }
}

extern "C" void kernel_launch(void* const* d_in, const int* in_sizes, int n_in,
                              void* d_out, int out_size, void* d_ws, size_t ws_size,
                              hipStream_t stream) {
    const float* z  = (const float*)d_in[0];
    const float* cb = (const float*)d_in[1];
    float* out      = (float*)d_out;
    char*  ws       = (char*)d_ws;

    double* loss_acc = (double*)ws;
    int*    counter  = (int*)(ws + 8);
    int*    done     = (int*)(ws + 12);
    float*  norms    = (float*)(ws + 64);
    short*  ehg      = (short*)(ws + 8192);
    short*  elg      = (short*)(ws + 139264);
    int*    worklist = (int*)(ws + 270336);

    int cap = WLCAP;
    long avail = ((long)ws_size - 270336) / 4;
    if (avail < cap) cap = (avail > 0) ? (int)avail : 0;

    vq_prep<<<dim3(KCODE / 16), dim3(256), 0, stream>>>(
        cb, norms, ehg, elg, loss_acc, counter, done);
    vq_main<<<dim3(N_VEC / BLK_ROWS), dim3(128), 0, stream>>>(
        z, cb, norms, ehg, elg, out, loss_acc, counter, worklist, cap);
    vq_rescue<<<dim3(512), dim3(256), 0, stream>>>(
        z, cb, out, loss_acc, counter, worklist, cap, done, out + (out_size - 1));
}